// Round 3
// baseline (768.756 us; speedup 1.0000x reference)
//
#include <hip/hip_runtime.h>

// VectorQuantizer: z (32,64,64,64) fp32, embedding_w (2048,64) fp32.
// Outputs concat: quantized_out (32,64,64,64) | indices (32,64,64) as float | loss (1)
//
// Numerics: bit-exact replication of the numpy fp32 reference (verified R1/R2, absmax 0):
//   S_n = pairwise64(z_n^2), b_k = pairwise64(w_k^2)  (numpy pairwise_sum order)
//   C_nk = sequential fp32 FMA chain over c=0..63 ascending (single chain per (n,k))
//   d = fp32(fp32(S + b) - fp32(2*C)), argmin first-index tie-break.
//
// R3 structure: LDS-free inner loop. One thread owns one full z row (64 VGPRs)
// for the whole K loop; w is read at wave-uniform addresses (derived only from
// blockIdx + loop IVs) so the compiler scalarizes to s_load -> SGPR broadcast
// into v_fma (1 SGPR operand allowed). Grid = 512 row-groups x 2 code-halves.
// Cross-block argmin merge: packed key (d_bits<<32 | k) + atomicMin in d_ws.
// d >= ~30 > 0 always, so positive-float bits are unsigned-monotone; low bits
// = k gives exact smallest-index tie-break. 0xAA ws poison = 0xAAAA... which
// exceeds any real key, so no explicit init pass is needed.

#define KCODES  2048
#define CDIM    64
#define OUT_Q   0
#define OUT_IDX 8388608
#define OUT_LOSS 8519680

__device__ __forceinline__ float pairwise64(const float a[64]) {
    float r[8];
#pragma unroll
    for (int j = 0; j < 8; ++j) r[j] = a[j];
#pragma unroll
    for (int m = 1; m < 8; ++m)
#pragma unroll
        for (int j = 0; j < 8; ++j) r[j] = __fadd_rn(r[j], a[m * 8 + j]);
    float s01 = __fadd_rn(r[0], r[1]);
    float s23 = __fadd_rn(r[2], r[3]);
    float s45 = __fadd_rn(r[4], r[5]);
    float s67 = __fadd_rn(r[6], r[7]);
    float s0123 = __fadd_rn(s01, s23);
    float s4567 = __fadd_rn(s45, s67);
    return __fadd_rn(s0123, s4567);
}

__device__ __forceinline__ float fc(const float4& v, int i) {
    return i == 0 ? v.x : (i == 1 ? v.y : (i == 2 ? v.z : v.w));
}

// ---------------- kernel A: b_k = pairwise64(w_k^2) ----------------
__global__ __launch_bounds__(256) void vq_bsum(const float* __restrict__ w,
                                               float* __restrict__ bsum) {
    int k = blockIdx.x * 256 + threadIdx.x;
    const float4* wr = (const float4*)(w + (size_t)k * CDIM);
    float a[64];
#pragma unroll
    for (int m = 0; m < 16; ++m) {
        float4 v = wr[m];
        a[4 * m + 0] = __fmul_rn(v.x, v.x);
        a[4 * m + 1] = __fmul_rn(v.y, v.y);
        a[4 * m + 2] = __fmul_rn(v.z, v.z);
        a[4 * m + 3] = __fmul_rn(v.w, v.w);
    }
    bsum[k] = pairwise64(a);
}

// ---------------- kernel B: main VQ (argmin only) ----------------
// grid 1024: blk>>1 = row-group (256 rows), blk&1 = code half (1024 codes).
// One thread = one row, full row resident in VGPRs.
__global__ __launch_bounds__(256, 4) void vq_main(const float* __restrict__ z,
                                                  const float* __restrict__ w,
                                                  const float* __restrict__ bsum,
                                                  unsigned long long* __restrict__ keys) {
    const int r     = (blockIdx.x >> 1) * 256 + threadIdx.x;   // global row
    const int kbase = (blockIdx.x & 1) * 1024;                 // wave-uniform

    // ---- load my row of z: coalesced across lanes (lanes = consecutive w) ----
    const float* zp = z + ((size_t)(r >> 12)) * 262144 + (size_t)(r & 4095);
    float zr_[64];
#pragma unroll
    for (int c = 0; c < 64; ++c) zr_[c] = zp[(size_t)c * 4096];

    // ---- S = numpy-pairwise sum of squares ----
    float a[64];
#pragma unroll
    for (int c = 0; c < 64; ++c) a[c] = __fmul_rn(zr_[c], zr_[c]);
    const float S = pairwise64(a);

    float dmin = __builtin_inff();
    int   kmin = 0;

    // ---- 256 quads of 4 codes; w addresses depend only on blockIdx/loop IVs ----
    for (int q = 0; q < 256; ++q) {
        const int k0 = kbase + q * 4;
        const float4* w0 = (const float4*)(w + (size_t)(k0 + 0) * CDIM);
        const float4* w1 = (const float4*)(w + (size_t)(k0 + 1) * CDIM);
        const float4* w2 = (const float4*)(w + (size_t)(k0 + 2) * CDIM);
        const float4* w3 = (const float4*)(w + (size_t)(k0 + 3) * CDIM);

        float acc0 = 0.f, acc1 = 0.f, acc2 = 0.f, acc3 = 0.f;
#pragma unroll
        for (int ch = 0; ch < 4; ++ch) {          // 16 dims per chunk
            float4 v0[4], v1[4], v2[4], v3[4];
#pragma unroll
            for (int u = 0; u < 4; ++u) {
                v0[u] = w0[4 * ch + u];
                v1[u] = w1[4 * ch + u];
                v2[u] = w2[4 * ch + u];
                v3[u] = w3[4 * ch + u];
            }
#pragma unroll
            for (int u = 0; u < 4; ++u)
#pragma unroll
                for (int e = 0; e < 4; ++e) {
                    const int c = 16 * ch + 4 * u + e;
                    acc0 = __builtin_fmaf(zr_[c], fc(v0[u], e), acc0);
                    acc1 = __builtin_fmaf(zr_[c], fc(v1[u], e), acc1);
                    acc2 = __builtin_fmaf(zr_[c], fc(v2[u], e), acc2);
                    acc3 = __builtin_fmaf(zr_[c], fc(v3[u], e), acc3);
                }
        }

        const float4 bq = *(const float4*)(bsum + k0);
        float d0 = __fsub_rn(__fadd_rn(S, bq.x), __fadd_rn(acc0, acc0));
        float d1 = __fsub_rn(__fadd_rn(S, bq.y), __fadd_rn(acc1, acc1));
        float d2 = __fsub_rn(__fadd_rn(S, bq.z), __fadd_rn(acc2, acc2));
        float d3 = __fsub_rn(__fadd_rn(S, bq.w), __fadd_rn(acc3, acc3));
        if (d0 < dmin) { dmin = d0; kmin = k0 + 0; }
        if (d1 < dmin) { dmin = d1; kmin = k0 + 1; }
        if (d2 < dmin) { dmin = d2; kmin = k0 + 2; }
        if (d3 < dmin) { dmin = d3; kmin = k0 + 3; }
    }

    const unsigned long long key =
        ((unsigned long long)__float_as_uint(dmin) << 32) | (unsigned int)kmin;
    atomicMin(&keys[r], key);
}

// ---------------- kernel C: epilogue (indices, quantized, loss partials) ----
__global__ __launch_bounds__(256) void vq_epi(const float* __restrict__ z,
                                              const float* __restrict__ w,
                                              const unsigned long long* __restrict__ keys,
                                              float* __restrict__ out,
                                              float* __restrict__ partial) {
    __shared__ int idxs[256];
    __shared__ double lred[4];
    const int bb = blockIdx.x;           // 0..511, rows [bb*256, bb*256+256)
    const int t  = threadIdx.x;
    const int r  = bb * 256 + t;

    const int k = (int)(keys[r] & 0xFFFFFFFFull);
    out[OUT_IDX + r] = (float)k;
    idxs[t] = k;
    __syncthreads();

    const size_t base = ((size_t)(r >> 12)) * 262144 + (size_t)((bb * 256) & 4095);
    double lacc = 0.0;
#pragma unroll
    for (int m = 0; m < 64; ++m) {
        int i  = t + 256 * m;            // 0..16383
        int c  = i >> 8;                 // 0..63
        int rr = i & 255;
        int kq = idxs[rr];
        float zv = z[base + (size_t)c * 4096 + rr];
        float q  = w[(size_t)kq * CDIM + c];
        float t1  = __fsub_rn(q, zv);            // quantized - zp
        float val = __fadd_rn(zv, t1);           // zp + (q - zp)
        out[OUT_Q + base + (size_t)c * 4096 + rr] = val;
        lacc += (double)__fmul_rn(t1, t1);
    }

#pragma unroll
    for (int off = 1; off < 64; off <<= 1) lacc += __shfl_xor(lacc, off, 64);
    if ((t & 63) == 0) lred[t >> 6] = lacc;
    __syncthreads();
    if (t == 0) {
        double tot = lred[0] + lred[1] + lred[2] + lred[3];
        partial[bb] = (float)(tot * (0.25 / 8388608.0));
    }
}

// ---------------- kernel D: reduce loss partials (512) ----------------
__global__ __launch_bounds__(256) void vq_loss(const float* __restrict__ partial,
                                               float* __restrict__ out) {
    int t = threadIdx.x;
    double s = (double)partial[t] + (double)partial[t + 256];
#pragma unroll
    for (int off = 1; off < 64; off <<= 1) s += __shfl_xor(s, off, 64);
    __shared__ double sr[4];
    if ((t & 63) == 0) sr[t >> 6] = s;
    __syncthreads();
    if (t == 0) out[OUT_LOSS] = (float)(sr[0] + sr[1] + sr[2] + sr[3]);
}

extern "C" void kernel_launch(void* const* d_in, const int* in_sizes, int n_in,
                              void* d_out, int out_size, void* d_ws, size_t ws_size,
                              hipStream_t stream) {
    (void)in_sizes; (void)n_in; (void)out_size; (void)ws_size;
    const float* z = (const float*)d_in[0];
    const float* w = (const float*)d_in[1];
    float* out     = (float*)d_out;

    // ws layout: keys (131072 x u64 = 1 MiB) | bsum (2048 f) | partial (512 f)
    unsigned long long* keys = (unsigned long long*)d_ws;
    float* bsum    = (float*)((char*)d_ws + 131072 * sizeof(unsigned long long));
    float* partial = bsum + KCODES;

    vq_bsum<<<8, 256, 0, stream>>>(w, bsum);
    // keys need no init: 0xAA poison = 0xAAAA... > any (positive d_bits<<32|k) key
    vq_main<<<1024, 256, 0, stream>>>(z, w, bsum, keys);
    vq_epi<<<512, 256, 0, stream>>>(z, w, keys, out, partial);
    vq_loss<<<1, 256, 0, stream>>>(partial, out);
}

// Round 4
// 455.900 us; speedup vs baseline: 1.6862x; 1.6862x over previous
//
#include <hip/hip_runtime.h>

// VectorQuantizer: z (32,64,64,64) fp32, embedding_w (2048,64) fp32.
// Outputs concat: quantized_out (32,64,64,64) | indices (32,64,64) as float | loss (1)
//
// Numerics: bit-exact replication of the numpy fp32 reference (verified R1-R3, absmax 0):
//   S_n = pairwise64(z_n^2), b_k = pairwise64(w_k^2)  (numpy pairwise_sum order)
//   C_nk = one sequential fp32 FMA chain over c=0..63 ascending per (n,k)
//   d = fp32(fp32(S + b) - fp32(2*C)), argmin first-index tie-break.
//
// R4: block = 256 rows. z-tile in LDS as row-pairs (float2) -> packed
// v_pk_fma_f32 over the row axis (no broadcast movs on the VGPR side; the
// packing never crosses the dim axis, so each (n,k) chain stays sequential
// and bit-exact). w + bsum read at wave-uniform addresses (readfirstlane'd
// wave id + loop IVs) -> scalar s_load path, zero LDS/VALU cost. Each wave
// sweeps 512 codes x 256 rows; per-row argmin merged via packed-key
// (d_bits<<32 | k) atomicMin in LDS (d > 0 always; scheme verified R3).
// Epilogue fused: thread t owns row t (indices, STE quantized write, loss).

#define KCODES   2048
#define CDIM     64
#define OUT_Q    0
#define OUT_IDX  8388608
#define OUT_LOSS 8519680
#define PSTR     132        // floats per pair-row: 64 dims * 2 + 4 pad (16B-aligned, 4-bank shift)

typedef float f2 __attribute__((ext_vector_type(2)));

__device__ __forceinline__ f2 fma2(f2 a, f2 b, f2 c) {
#if __has_builtin(__builtin_elementwise_fma)
    return __builtin_elementwise_fma(a, b, c);
#else
    f2 r; r.x = __builtin_fmaf(a.x, b.x, c.x); r.y = __builtin_fmaf(a.y, b.y, c.y);
    return r;
#endif
}

__device__ __forceinline__ float pairwise64(const float a[64]) {
    float r[8];
#pragma unroll
    for (int j = 0; j < 8; ++j) r[j] = a[j];
#pragma unroll
    for (int m = 1; m < 8; ++m)
#pragma unroll
        for (int j = 0; j < 8; ++j) r[j] = __fadd_rn(r[j], a[m * 8 + j]);
    float s01 = __fadd_rn(r[0], r[1]);
    float s23 = __fadd_rn(r[2], r[3]);
    float s45 = __fadd_rn(r[4], r[5]);
    float s67 = __fadd_rn(r[6], r[7]);
    return __fadd_rn(__fadd_rn(s01, s23), __fadd_rn(s45, s67));
}

__device__ __forceinline__ float fc(const float4& v, int i) {
    return i == 0 ? v.x : (i == 1 ? v.y : (i == 2 ? v.z : v.w));
}

// ---------------- kernel A: b_k = pairwise64(w_k^2) ----------------
__global__ __launch_bounds__(256) void vq_bsum(const float* __restrict__ w,
                                               float* __restrict__ bsum) {
    int k = blockIdx.x * 256 + threadIdx.x;
    const float4* wr = (const float4*)(w + (size_t)k * CDIM);
    float a[64];
#pragma unroll
    for (int m = 0; m < 16; ++m) {
        float4 v = wr[m];
        a[4 * m + 0] = __fmul_rn(v.x, v.x);
        a[4 * m + 1] = __fmul_rn(v.y, v.y);
        a[4 * m + 2] = __fmul_rn(v.z, v.z);
        a[4 * m + 3] = __fmul_rn(v.w, v.w);
    }
    bsum[k] = pairwise64(a);
}

// ---------------- kernel B: main VQ (fused argmin + epilogue) ----------------
__global__ __launch_bounds__(256, 2) void vq_main(const float* __restrict__ z,
                                                  const float* __restrict__ w,
                                                  const float* __restrict__ bsum,
                                                  float* __restrict__ out,
                                                  float* __restrict__ partial) {
    __shared__ float zsh[128 * PSTR];               // 67.6 KB: zsh[pair][dim] as float2
    __shared__ float Ss[256];
    __shared__ unsigned long long skey[256];
    __shared__ double lred[4];

    const int t  = threadIdx.x;
    const int l  = t & 63;                          // lane
    const int bb = blockIdx.x;                      // 0..511; rows [bb*256, bb*256+256)
    const size_t zbase = (size_t)(bb >> 4) * 262144 + (size_t)(bb & 15) * 256;

    // ---- stage z tile: zsh[p][c] = (z_row{2p}_c, z_row{2p+1}_c) ----
#pragma unroll
    for (int m = 0; m < 32; ++m) {
        int i = m * 256 + t;                        // 0..8191
        int p = i & 127;
        int c = i >> 7;
        f2 v = *(const f2*)(z + zbase + (size_t)c * 4096 + 2 * p);
        *(f2*)&zsh[p * PSTR + 2 * c] = v;
    }
    __syncthreads();

    // ---- S per row (numpy pairwise of squares); init argmin keys ----
    {
        float a[64];
        const int pb = (t >> 1) * PSTR + (t & 1);
#pragma unroll
        for (int c = 0; c < 64; ++c) {
            float v = zsh[pb + 2 * c];
            a[c] = __fmul_rn(v, v);
        }
        Ss[t] = pairwise64(a);
        skey[t] = 0xFFFFFFFFFFFFFFFFull;
    }
    __syncthreads();

    f2 Sp0, Sp1;
    Sp0.x = Ss[2 * l];       Sp0.y = Ss[2 * l + 1];
    Sp1.x = Ss[2 * l + 128]; Sp1.y = Ss[2 * l + 129];

    // wave-uniform code range: wave wv handles codes [wv*512, wv*512+512)
    const int kwave = __builtin_amdgcn_readfirstlane(t >> 6) * 512;

    float dmin0 = __builtin_inff(), dmin1 = dmin0, dmin2 = dmin0, dmin3 = dmin0;
    int   kmin0 = 0, kmin1 = 0, kmin2 = 0, kmin3 = 0;

    const int zoffA = l * PSTR;
    const int zoffB = (l + 64) * PSTR;

    for (int ks = 0; ks < 64; ++ks) {
        const int k0 = kwave + ks * 8;              // wave-uniform
        const float* wk = w + (size_t)k0 * CDIM;

        f2 acc0[8], acc1[8];
#pragma unroll
        for (int j = 0; j < 8; ++j) { acc0[j] = (f2)0.f; acc1[j] = (f2)0.f; }

#pragma unroll 4
        for (int c0 = 0; c0 < 64; c0 += 4) {
            // z row-pairs, dims c0..c0+3 (x,y = dim c; z,w = dim c+1)
            float4 a0 = *(const float4*)&zsh[zoffA + 2 * c0];
            float4 a1 = *(const float4*)&zsh[zoffA + 2 * c0 + 4];
            float4 b0 = *(const float4*)&zsh[zoffB + 2 * c0];
            float4 b1 = *(const float4*)&zsh[zoffB + 2 * c0 + 4];
            f2 aL0; aL0.x = a0.x; aL0.y = a0.y;     // pairA @ c0
            f2 aH0; aH0.x = a0.z; aH0.y = a0.w;     // pairA @ c0+1
            f2 aL1; aL1.x = a1.x; aL1.y = a1.y;     // pairA @ c0+2
            f2 aH1; aH1.x = a1.z; aH1.y = a1.w;     // pairA @ c0+3
            f2 bL0; bL0.x = b0.x; bL0.y = b0.y;
            f2 bH0; bH0.x = b0.z; bH0.y = b0.w;
            f2 bL1; bL1.x = b1.x; bL1.y = b1.y;
            f2 bH1; bH1.x = b1.z; bH1.y = b1.w;

#pragma unroll
            for (int j = 0; j < 8; ++j) {
                // wave-uniform address -> s_load_dwordx4 (scalar pipe)
                float4 wc = *(const float4*)(wk + (size_t)j * CDIM + c0);
                f2 w0 = (f2)(wc.x);                 // splat
                f2 w1 = (f2)(wc.y);
                f2 w2 = (f2)(wc.z);
                f2 w3 = (f2)(wc.w);
                // dims ascending -> sequential chain per (row, code), bit-exact
                acc0[j] = fma2(aL0, w0, acc0[j]);
                acc0[j] = fma2(aH0, w1, acc0[j]);
                acc0[j] = fma2(aL1, w2, acc0[j]);
                acc0[j] = fma2(aH1, w3, acc0[j]);
                acc1[j] = fma2(bL0, w0, acc1[j]);
                acc1[j] = fma2(bH0, w1, acc1[j]);
                acc1[j] = fma2(bL1, w2, acc1[j]);
                acc1[j] = fma2(bH1, w3, acc1[j]);
            }
        }

        // d = fp32((S + b) - 2*C); strict < keeps earliest k (k ascending)
        const float4 bq0 = *(const float4*)(bsum + k0);      // uniform -> s_load
        const float4 bq1 = *(const float4*)(bsum + k0 + 4);
#pragma unroll
        for (int j = 0; j < 8; ++j) {
            float bj = j < 4 ? fc(bq0, j) : fc(bq1, j - 4);
            f2 bb2 = (f2)(bj);
            f2 dA = (Sp0 + bb2) - (acc0[j] + acc0[j]);
            f2 dB = (Sp1 + bb2) - (acc1[j] + acc1[j]);
            int kg = k0 + j;
            if (dA.x < dmin0) { dmin0 = dA.x; kmin0 = kg; }
            if (dA.y < dmin1) { dmin1 = dA.y; kmin1 = kg; }
            if (dB.x < dmin2) { dmin2 = dB.x; kmin2 = kg; }
            if (dB.y < dmin3) { dmin3 = dB.y; kmin3 = kg; }
        }
    }

    // ---- merge per-row argmin across the 4 waves (packed key, LDS atomic) ----
    atomicMin(&skey[2 * l],       ((unsigned long long)__float_as_uint(dmin0) << 32) | (unsigned int)kmin0);
    atomicMin(&skey[2 * l + 1],   ((unsigned long long)__float_as_uint(dmin1) << 32) | (unsigned int)kmin1);
    atomicMin(&skey[2 * l + 128], ((unsigned long long)__float_as_uint(dmin2) << 32) | (unsigned int)kmin2);
    atomicMin(&skey[2 * l + 129], ((unsigned long long)__float_as_uint(dmin3) << 32) | (unsigned int)kmin3);
    __syncthreads();

    // ---- epilogue: thread t owns row t ----
    const int kq = (int)(skey[t] & 0xFFFFFFFFull);
    out[OUT_IDX + (size_t)bb * 256 + t] = (float)kq;

    const float* wq = w + (size_t)kq * CDIM;
    const int pb = (t >> 1) * PSTR + (t & 1);
    double lacc = 0.0;
#pragma unroll
    for (int c = 0; c < 64; ++c) {
        float zv = zsh[pb + 2 * c];
        float q  = wq[c];
        float d1  = __fsub_rn(q, zv);               // quantized - zp
        float val = __fadd_rn(zv, d1);              // zp + (q - zp)
        out[OUT_Q + zbase + (size_t)c * 4096 + t] = val;
        lacc += (double)__fmul_rn(d1, d1);
    }

#pragma unroll
    for (int off = 1; off < 64; off <<= 1) lacc += __shfl_xor(lacc, off, 64);
    if ((t & 63) == 0) lred[t >> 6] = lacc;
    __syncthreads();
    if (t == 0) {
        double tot = lred[0] + lred[1] + lred[2] + lred[3];
        partial[bb] = (float)(tot * (0.25 / 8388608.0));
    }
}

// ---------------- kernel C: reduce loss partials (512) ----------------
__global__ __launch_bounds__(256) void vq_loss(const float* __restrict__ partial,
                                               float* __restrict__ out) {
    int t = threadIdx.x;
    double s = (double)partial[t] + (double)partial[t + 256];
#pragma unroll
    for (int off = 1; off < 64; off <<= 1) s += __shfl_xor(s, off, 64);
    __shared__ double sr[4];
    if ((t & 63) == 0) sr[t >> 6] = s;
    __syncthreads();
    if (t == 0) out[OUT_LOSS] = (float)(sr[0] + sr[1] + sr[2] + sr[3]);
}

extern "C" void kernel_launch(void* const* d_in, const int* in_sizes, int n_in,
                              void* d_out, int out_size, void* d_ws, size_t ws_size,
                              hipStream_t stream) {
    (void)in_sizes; (void)n_in; (void)out_size; (void)ws_size;
    const float* z = (const float*)d_in[0];
    const float* w = (const float*)d_in[1];
    float* out     = (float*)d_out;

    float* bsum    = (float*)d_ws;                  // 2048 floats
    float* partial = bsum + KCODES;                 // 512 floats

    vq_bsum<<<8, 256, 0, stream>>>(w, bsum);
    vq_main<<<512, 256, 0, stream>>>(z, w, bsum, out, partial);
    vq_loss<<<1, 256, 0, stream>>>(partial, out);
}